// Round 2
// baseline (1706.299 us; speedup 1.0000x reference)
//
#include <hip/hip_runtime.h>

#define B_    64
#define N_    100
#define D_    32
#define F0    96
#define F1    160
#define F2    192
#define H0    224   // F2 + D
#define HID   256
#define FOUT  32

typedef unsigned short u16;
typedef unsigned int   u32;
typedef u16 __attribute__((ext_vector_type(4))) u16x4;

__device__ __forceinline__ float bfu2f(u16 u) {
    return __uint_as_float(((u32)u) << 16);
}
__device__ __forceinline__ u16 f2bfu(float f) {
    u32 u = __float_as_uint(f);
    u += 0x7fffu + ((u >> 16) & 1u);   // round-to-nearest-even
    return (u16)(u >> 16);
}
__device__ __forceinline__ float lrelu(float v) { return v > 0.f ? v : 0.2f * v; }

// ---- layer 1: A1[j][f] = lrelu(sum_k A0[j][k] * W1[k][f] + b1[f]) ----
template<int NT>
__device__ __forceinline__ void layer1_sweep(int jb, int jj, int ff,
        const u16* __restrict__ sA0, u16* __restrict__ sA1,
        const float* __restrict__ w1, const float* bv) {
    float acc[NT][5];
    int jrow[NT];
    #pragma unroll
    for (int jt = 0; jt < NT; ++jt) {
        int j = jb + jt * 16 + jj;
        jrow[jt] = (j < N_) ? j : 0;   // clamp for safe LDS reads; stores masked below
        #pragma unroll
        for (int s = 0; s < 5; ++s) acc[jt][s] = 0.f;
    }
    for (int k = 0; k < F0; k += 4) {
        float a[NT][4];
        #pragma unroll
        for (int jt = 0; jt < NT; ++jt) {
            u16x4 q = *(const u16x4*)(sA0 + jrow[jt] * F0 + k);
            #pragma unroll
            for (int kk = 0; kk < 4; ++kk) a[jt][kk] = bfu2f(q[kk]);
        }
        #pragma unroll
        for (int kk = 0; kk < 4; ++kk) {
            float wv[5];
            #pragma unroll
            for (int s = 0; s < 5; ++s) wv[s] = w1[(k + kk) * F1 + ff + 32 * s];
            #pragma unroll
            for (int jt = 0; jt < NT; ++jt)
                #pragma unroll
                for (int s = 0; s < 5; ++s)
                    acc[jt][s] = fmaf(a[jt][kk], wv[s], acc[jt][s]);
        }
    }
    #pragma unroll
    for (int jt = 0; jt < NT; ++jt) {
        int j = jb + jt * 16 + jj;
        if (j < N_) {
            #pragma unroll
            for (int s = 0; s < 5; ++s)
                sA1[j * F1 + ff + 32 * s] = f2bfu(lrelu(acc[jt][s] + bv[s]));
        }
    }
}

// ---- layer 2 + aggregation: aggp[f] += lrelu(sum_k A1[j][k]*W2[k][f] + b2[f]) ----
template<int NT>
__device__ __forceinline__ void layer2_sweep(int jb, int jj, int ff,
        const u16* __restrict__ sA1, const float* __restrict__ w2,
        const float* bv, float* aggp) {
    float acc[NT][6];
    int jrow[NT];
    #pragma unroll
    for (int jt = 0; jt < NT; ++jt) {
        int j = jb + jt * 16 + jj;
        jrow[jt] = (j < N_) ? j : 0;
        #pragma unroll
        for (int s = 0; s < 6; ++s) acc[jt][s] = 0.f;
    }
    for (int k = 0; k < F1; k += 4) {
        float a[NT][4];
        #pragma unroll
        for (int jt = 0; jt < NT; ++jt) {
            u16x4 q = *(const u16x4*)(sA1 + jrow[jt] * F1 + k);
            #pragma unroll
            for (int kk = 0; kk < 4; ++kk) a[jt][kk] = bfu2f(q[kk]);
        }
        #pragma unroll
        for (int kk = 0; kk < 4; ++kk) {
            float wv[6];
            #pragma unroll
            for (int s = 0; s < 6; ++s) wv[s] = w2[(k + kk) * F2 + ff + 32 * s];
            #pragma unroll
            for (int jt = 0; jt < NT; ++jt)
                #pragma unroll
                for (int s = 0; s < 6; ++s)
                    acc[jt][s] = fmaf(a[jt][kk], wv[s], acc[jt][s]);
        }
    }
    #pragma unroll
    for (int jt = 0; jt < NT; ++jt) {
        int j = jb + jt * 16 + jj;
        if (j < N_) {
            #pragma unroll
            for (int s = 0; s < 6; ++s)
                aggp[s] += lrelu(acc[jt][s] + bv[s]);
        }
    }
}

__global__ __launch_bounds__(512, 1) void mp_kernel(
    const float* __restrict__ x,
    const float* __restrict__ few0, const float* __restrict__ feb0,
    const float* __restrict__ few1, const float* __restrict__ feb1,
    const float* __restrict__ few2, const float* __restrict__ feb2,
    const float* __restrict__ fnw0, const float* __restrict__ fnb0,
    const float* __restrict__ fnw1, const float* __restrict__ fnb1,
    const float* __restrict__ fnw2, const float* __restrict__ fnb2,
    float* __restrict__ out)
{
    const int i   = blockIdx.x;      // node index
    const int b   = blockIdx.y;      // batch index
    const int tid = threadIdx.x;
    const int ff  = tid & 31;        // feature lane 0..31
    const int jj  = tid >> 5;        // j-subtile 0..15

    __shared__ __align__(16) float sXf[N_ * D_];  // 12800 B : x[b] rows (fp32)
    __shared__ __align__(16) u16  sA0[N_ * F0];   // 19200 B : edge layer-0 act (bf16)
    __shared__ __align__(16) u16  sA1[N_ * F1];   // 32000 B : edge layer-1 act (bf16)
    __shared__ __align__(16) float sU[F0];        //   384 B : u_i = x_i @ W0_top
    // total static LDS = 64384 B

    // ---- stage x[b] (100x32 fp32 = 800 float4) ----
    {
        const float4* src = (const float4*)(x + b * (N_ * D_));
        float4* dst = (float4*)sXf;
        #pragma unroll
        for (int t = tid; t < (N_ * D_) / 4; t += 512) dst[t] = src[t];
    }
    __syncthreads();

    // ---- u[k] = sum_d x[b,i,d] * W0[d][k]  (top half of W0) ----
    if (tid < F0) {
        float acc = 0.f;
        #pragma unroll
        for (int d = 0; d < D_; ++d)
            acc = fmaf(sXf[i * D_ + d], few0[d * F0 + tid], acc);
        sU[tid] = acc;
    }
    __syncthreads();

    // ---- A0[j][k] = lrelu(u[k] + sum_d x[b,j,d]*W0[32+d][k] + b0[k]) ----
    for (int e = tid; e < N_ * F0; e += 512) {
        int j = e / F0, k = e - j * F0;
        float acc = sU[k] + feb0[k];
        #pragma unroll
        for (int d = 0; d < D_; ++d)
            acc = fmaf(sXf[j * D_ + d], few0[(D_ + d) * F0 + k], acc);
        sA0[e] = f2bfu(lrelu(acc));
    }
    __syncthreads();

    // ---- edge layer 1 ----
    {
        float bv[5];
        #pragma unroll
        for (int s = 0; s < 5; ++s) bv[s] = feb1[ff + 32 * s];
        layer1_sweep<4>(0,  jj, ff, sA0, sA1, few1, bv);
        layer1_sweep<3>(64, jj, ff, sA0, sA1, few1, bv);
    }
    __syncthreads();

    // ---- edge layer 2 + per-thread partial aggregation over j ----
    float aggp[6];
    #pragma unroll
    for (int s = 0; s < 6; ++s) aggp[s] = 0.f;
    {
        float bv[6];
        #pragma unroll
        for (int s = 0; s < 6; ++s) bv[s] = feb2[ff + 32 * s];
        layer2_sweep<4>(0,  jj, ff, sA1, few2, bv, aggp);
        layer2_sweep<3>(64, jj, ff, sA1, few2, bv, aggp);
    }

    // ---- reduce aggregation over the 16 jj groups (sAgg aliases dead sA0) ----
    float* sAgg = (float*)sA0;            // 16*192*4 = 12288 B <= 19200 B
    #pragma unroll
    for (int s = 0; s < 6; ++s) sAgg[jj * F2 + ff + 32 * s] = aggp[s];
    __syncthreads();

    float* sH  = (float*)sA1;             // 224+256+256 floats = 2944 B <= 32000 B
    float* sH1 = sH + H0;
    float* sH2 = sH1 + HID;
    if (tid < F2) {
        float s = 0.f;
        #pragma unroll
        for (int r = 0; r < 16; ++r) s += sAgg[r * F2 + tid];
        sH[tid] = s;
    } else if (tid < H0) {
        sH[tid] = sXf[i * D_ + (tid - F2)];   // concat x_i
    }
    __syncthreads();

    // ---- node layer 0: 224 -> 256, leaky relu ----
    if (tid < HID) {
        float a0 = fnb0[tid], a1 = 0.f;
        #pragma unroll 8
        for (int k = 0; k < H0; k += 2) {
            a0 = fmaf(sH[k],     fnw0[k * HID + tid],       a0);
            a1 = fmaf(sH[k + 1], fnw0[(k + 1) * HID + tid], a1);
        }
        sH1[tid] = lrelu(a0 + a1);
    }
    __syncthreads();

    // ---- node layer 1: 256 -> 256, leaky relu ----
    if (tid < HID) {
        float a0 = fnb1[tid], a1 = 0.f;
        #pragma unroll 8
        for (int k = 0; k < HID; k += 2) {
            a0 = fmaf(sH1[k],     fnw1[k * HID + tid],       a0);
            a1 = fmaf(sH1[k + 1], fnw1[(k + 1) * HID + tid], a1);
        }
        sH2[tid] = lrelu(a0 + a1);
    }
    __syncthreads();

    // ---- node layer 2: 256 -> 32, linear ----
    if (tid < FOUT) {
        float a0 = fnb2[tid], a1 = 0.f;
        #pragma unroll 8
        for (int k = 0; k < HID; k += 2) {
            a0 = fmaf(sH2[k],     fnw2[k * FOUT + tid],       a0);
            a1 = fmaf(sH2[k + 1], fnw2[(k + 1) * FOUT + tid], a1);
        }
        out[(b * N_ + i) * FOUT + tid] = a0 + a1;
    }
}

extern "C" void kernel_launch(void* const* d_in, const int* in_sizes, int n_in,
                              void* d_out, int out_size, void* d_ws, size_t ws_size,
                              hipStream_t stream) {
    const float* x    = (const float*)d_in[0];
    const float* few0 = (const float*)d_in[1];
    const float* feb0 = (const float*)d_in[2];
    const float* few1 = (const float*)d_in[3];
    const float* feb1 = (const float*)d_in[4];
    const float* few2 = (const float*)d_in[5];
    const float* feb2 = (const float*)d_in[6];
    const float* fnw0 = (const float*)d_in[7];
    const float* fnb0 = (const float*)d_in[8];
    const float* fnw1 = (const float*)d_in[9];
    const float* fnb1 = (const float*)d_in[10];
    const float* fnw2 = (const float*)d_in[11];
    const float* fnb2 = (const float*)d_in[12];

    mp_kernel<<<dim3(N_, B_), 512, 0, stream>>>(
        x, few0, feb0, few1, feb1, few2, feb2,
        fnw0, fnb0, fnw1, fnb1, fnw2, fnb2,
        (float*)d_out);
}

// Round 3
// 209.205 us; speedup vs baseline: 8.1561x; 8.1561x over previous
//
#include <hip/hip_runtime.h>

#define B_    64
#define N_    100
#define D_    32
#define F0    96
#define F1    160
#define F2    192
#define HID   256
#define FOUT  32

typedef unsigned short u16;
typedef unsigned int   u32;
typedef u16   u16x8 __attribute__((ext_vector_type(8)));
typedef __bf16 bf16x8 __attribute__((ext_vector_type(8)));
typedef float  fx4   __attribute__((ext_vector_type(4)));

__device__ __forceinline__ u16 f2bfu(float f) {
    u32 u = __float_as_uint(f);
    u += 0x7fffu + ((u >> 16) & 1u);   // RNE
    return (u16)(u >> 16);
}
__device__ __forceinline__ float lrelu(float v) { return v > 0.f ? v : 0.2f * v; }

__device__ __forceinline__ bf16x8 fragLds(const u16* p) {
    return __builtin_bit_cast(bf16x8, *(const u16x8*)p);
}
__device__ __forceinline__ bf16x8 fragGbl(const u16* __restrict__ p) {
    return __builtin_bit_cast(bf16x8, *(const u16x8*)p);
}
#define MFMA(a, b, c) __builtin_amdgcn_mfma_f32_16x16x32_bf16((a), (b), (c), 0, 0, 0)

// ---- ws layout (bytes) ----
#define OFF_P     0u
#define OFF_V     2457600u     // 6400*96*4
#define OFF_AGG   4915200u     // + 6400*96*4
#define OFF_PACK  7372800u     // + 6400*192*2
// packed weights (u16 element offsets within pack region):
#define PK_W1     0            // 96x160  -> 15360
#define PK_W2     15360        // 160x192 -> 30720
#define PK_N0     46080        // 224x256 -> 57344
#define PK_N1     103424       // 256x256 -> 65536
#define PK_N2     168960       // 256x32  -> 8192
#define PK_TOTAL  177152

#define PV_BLOCKS 2400         // 6400*192 / 512
#define PACK_BLOCKS 346        // 177152 / 512

// ============================ prep ============================
__global__ __launch_bounds__(512) void prep_kernel(
    const float* __restrict__ x,
    const float* __restrict__ few0, const float* __restrict__ feb0,
    const float* __restrict__ few1, const float* __restrict__ few2,
    const float* __restrict__ fnw0, const float* __restrict__ fnw1,
    const float* __restrict__ fnw2,
    float* __restrict__ P, float* __restrict__ V, u16* __restrict__ wpack)
{
    const int blk = blockIdx.x, tid = threadIdx.x;
    if (blk < PV_BLOCKS) {
        int o = blk * 512 + tid;           // < 6400*192
        int r = o / 192, h = o - r * 192;
        const float* xr = x + r * D_;
        if (h < F0) {
            float acc = feb0[h];
            #pragma unroll
            for (int d = 0; d < D_; ++d) acc = fmaf(xr[d], few0[d * F0 + h], acc);
            P[r * F0 + h] = acc;
        } else {
            int k = h - F0;
            float acc = 0.f;
            #pragma unroll
            for (int d = 0; d < D_; ++d) acc = fmaf(xr[d], few0[(D_ + d) * F0 + k], acc);
            V[r * F0 + k] = acc;
        }
    } else {
        int p = (blk - PV_BLOCKS) * 512 + tid;   // < 177152
        const float* src; int start, Ncols, NT;
        if (p < PK_W2)      { start = PK_W1; src = few1; Ncols = F1;   NT = 10; }
        else if (p < PK_N0) { start = PK_W2; src = few2; Ncols = F2;   NT = 12; }
        else if (p < PK_N1) { start = PK_N0; src = fnw0; Ncols = HID;  NT = 16; }
        else if (p < PK_N2) { start = PK_N1; src = fnw1; Ncols = HID;  NT = 16; }
        else                { start = PK_N2; src = fnw2; Ncols = FOUT; NT = 2;  }
        int local = p - start;
        int j = local & 7, lane = (local >> 3) & 63, rest = local >> 9;
        int nt = rest % NT, kt = rest / NT;
        int n = 16 * nt + (lane & 15);
        int k = 32 * kt + 8 * (lane >> 4) + j;
        wpack[p] = f2bfu(src[k * Ncols + n]);
    }
}

// ============================ edge ============================
// one block per (b,i); 8 waves: wm = wv>>2 (m-group), wn = wv&3 (n-group)
__global__ __launch_bounds__(512, 4) void edge_kernel(
    const float* __restrict__ P, const float* __restrict__ V,
    const u16* __restrict__ W1p, const u16* __restrict__ W2p,
    const float* __restrict__ feb1, const float* __restrict__ feb2,
    u16* __restrict__ agg)
{
    const int i = blockIdx.x, b = blockIdx.y;
    const int tid = threadIdx.x, ld = tid & 63, wv = tid >> 6;
    const int wn = wv & 3, wm = wv >> 2;
    const int row = b * N_ + i;

    __shared__ __align__(16) u16  sA0p[7 * 3 * 512];   // 21504 B
    __shared__ __align__(16) u16  sA1p[7 * 5 * 512];   // 35840 B
    __shared__ __align__(16) float sP[F0];
    __shared__ __align__(16) float sAggP[2 * F2];      // [wm][f]

    if (tid < F0) sP[tid] = P[row * F0 + tid];
    __syncthreads();

    // ---- A0 packed build: A0[j][k] = lrelu(P[i,k] + V[j,k]); pad rows -> 0 ----
    {
        const float* Vb = V + b * N_ * F0;
        #pragma unroll
        for (int s = 0; s < 21; ++s) {
            int e = tid + 512 * s;
            int j = e & 7, lane = (e >> 3) & 63, rest = e >> 9;
            int kt = rest % 3, mt = rest / 3;
            int k = 32 * kt + 8 * (lane >> 4) + j;
            int m = 16 * mt + (lane & 15);
            float v = 0.f;
            if (m < N_) v = lrelu(sP[k] + Vb[m * F0 + k]);
            sA0p[e] = f2bfu(v);
        }
    }
    __syncthreads();

    const int mtB = wm ? 4 : 0, mtE = wm ? 7 : 4;
    const int c = ld & 15, rlo = (ld >> 4) * 4;

    // ---- edge layer 1: [112x96] @ [96x160] -> sA1p (packed-A for layer 2) ----
    {
        const int nCnt = (wn < 2) ? 3 : 2;
        bf16x8 bw[3][3]; float bias[3];
        #pragma unroll
        for (int t = 0; t < 3; ++t) if (t < nCnt) {
            int nt = wn + 4 * t;
            bias[t] = feb1[16 * nt + c];
            #pragma unroll
            for (int kt = 0; kt < 3; ++kt)
                bw[t][kt] = fragGbl(W1p + (size_t)((kt * 10 + nt) * 64 + ld) * 8);
        }
        for (int mt = mtB; mt < mtE; ++mt) {
            bf16x8 a[3];
            #pragma unroll
            for (int kt = 0; kt < 3; ++kt)
                a[kt] = fragLds(sA0p + ((mt * 3 + kt) * 64 + ld) * 8);
            fx4 acc[3];
            #pragma unroll
            for (int t = 0; t < 3; ++t) acc[t] = (fx4){0.f, 0.f, 0.f, 0.f};
            #pragma unroll
            for (int kt = 0; kt < 3; ++kt)
                #pragma unroll
                for (int t = 0; t < 3; ++t)
                    if (t < nCnt) acc[t] = MFMA(a[kt], bw[t][kt], acc[t]);
            #pragma unroll
            for (int t = 0; t < 3; ++t) if (t < nCnt) {
                int f = 16 * (wn + 4 * t) + c;
                int kt2 = f >> 5, lq = (f >> 3) & 3, j2 = f & 7;
                #pragma unroll
                for (int r = 0; r < 4; ++r) {
                    float val = lrelu(acc[t][r] + bias[t]);
                    int lane2 = (rlo + r) + 16 * lq;
                    sA1p[((mt * 5 + kt2) * 64 + lane2) * 8 + j2] = f2bfu(val);
                }
            }
        }
    }
    __syncthreads();

    // ---- edge layer 2 + fused aggregation over j ----
    {
        bf16x8 bw[3][5]; float bias[3];
        float aggp[3] = {0.f, 0.f, 0.f};
        #pragma unroll
        for (int t = 0; t < 3; ++t) {
            int nt = wn + 4 * t;
            bias[t] = feb2[16 * nt + c];
            #pragma unroll
            for (int kt = 0; kt < 5; ++kt)
                bw[t][kt] = fragGbl(W2p + (size_t)((kt * 12 + nt) * 64 + ld) * 8);
        }
        for (int mt = mtB; mt < mtE; ++mt) {
            bf16x8 a[5];
            #pragma unroll
            for (int kt = 0; kt < 5; ++kt)
                a[kt] = fragLds(sA1p + ((mt * 5 + kt) * 64 + ld) * 8);
            fx4 acc[3];
            #pragma unroll
            for (int t = 0; t < 3; ++t) acc[t] = (fx4){0.f, 0.f, 0.f, 0.f};
            #pragma unroll
            for (int kt = 0; kt < 5; ++kt)
                #pragma unroll
                for (int t = 0; t < 3; ++t)
                    acc[t] = MFMA(a[kt], bw[t][kt], acc[t]);
            // rows m = 16*mt + rlo + r ; mask out pad rows (>=100)
            bool ok = (mt < 6) || (rlo == 0);
            if (ok) {
                #pragma unroll
                for (int t = 0; t < 3; ++t)
                    #pragma unroll
                    for (int r = 0; r < 4; ++r)
                        aggp[t] += lrelu(acc[t][r] + bias[t]);
            }
        }
        #pragma unroll
        for (int t = 0; t < 3; ++t) {
            aggp[t] += __shfl_xor(aggp[t], 16, 64);
            aggp[t] += __shfl_xor(aggp[t], 32, 64);
        }
        if (ld < 16) {
            #pragma unroll
            for (int t = 0; t < 3; ++t)
                sAggP[wm * F2 + 16 * (wn + 4 * t) + ld] = aggp[t];
        }
    }
    __syncthreads();

    if (tid < F2) {
        float v = sAggP[tid] + sAggP[F2 + tid];
        agg[(size_t)row * F2 + tid] = f2bfu(v);
    }
}

// ============================ node ============================
// 200 blocks x 32 rows; 3 chained MFMA GEMMs, zero padding anywhere
__global__ __launch_bounds__(512, 4) void node_kernel(
    const u16* __restrict__ agg, const float* __restrict__ x,
    const u16* __restrict__ n0p, const u16* __restrict__ n1p,
    const u16* __restrict__ n2p,
    const float* __restrict__ fnb0, const float* __restrict__ fnb1,
    const float* __restrict__ fnb2,
    float* __restrict__ out)
{
    const int blk = blockIdx.x;
    const int tid = threadIdx.x, ld = tid & 63, wv = tid >> 6;
    const int wn = wv & 3, mt = wv >> 2;   // 2 m-groups x 4 n-groups
    const int c = ld & 15, rlo = (ld >> 4) * 4;

    __shared__ __align__(16) u16 sH0p[2 * 7 * 512];   // 14336 B
    __shared__ __align__(16) u16 sH1p[2 * 8 * 512];   // 16384 B
    __shared__ __align__(16) u16 sH2p[2 * 8 * 512];   // 16384 B

    // ---- stage H0 = [agg | x] packed-A ----
    #pragma unroll
    for (int s = 0; s < 14; ++s) {
        int e = tid + 512 * s;
        int j = e & 7, lane = (e >> 3) & 63, rest = e >> 9;
        int kt = rest % 7, mtt = rest / 7;
        int k = 32 * kt + 8 * (lane >> 4) + j;
        int m = 16 * mtt + (lane & 15);
        int g = 32 * blk + m;
        u16 val = (k < F2) ? agg[(size_t)g * F2 + k]
                           : f2bfu(x[(size_t)g * D_ + (k - F2)]);
        sH0p[e] = val;
    }
    __syncthreads();

    // ---- node layer 0: K=224 (7 kt), N=256 (16 nt), lrelu ----
    {
        fx4 acc[4];
        #pragma unroll
        for (int t = 0; t < 4; ++t) acc[t] = (fx4){0.f, 0.f, 0.f, 0.f};
        for (int kt = 0; kt < 7; ++kt) {
            bf16x8 a = fragLds(sH0p + ((mt * 7 + kt) * 64 + ld) * 8);
            #pragma unroll
            for (int t = 0; t < 4; ++t) {
                bf16x8 bw = fragGbl(n0p + (size_t)((kt * 16 + wn + 4 * t) * 64 + ld) * 8);
                acc[t] = MFMA(a, bw, acc[t]);
            }
        }
        #pragma unroll
        for (int t = 0; t < 4; ++t) {
            int f = 16 * (wn + 4 * t) + c;
            float bias = fnb0[f];
            int kt2 = f >> 5, lq = (f >> 3) & 3, j2 = f & 7;
            #pragma unroll
            for (int r = 0; r < 4; ++r) {
                float val = lrelu(acc[t][r] + bias);
                sH1p[((mt * 8 + kt2) * 64 + (rlo + r) + 16 * lq) * 8 + j2] = f2bfu(val);
            }
        }
    }
    __syncthreads();

    // ---- node layer 1: K=256 (8 kt), N=256, lrelu ----
    {
        fx4 acc[4];
        #pragma unroll
        for (int t = 0; t < 4; ++t) acc[t] = (fx4){0.f, 0.f, 0.f, 0.f};
        for (int kt = 0; kt < 8; ++kt) {
            bf16x8 a = fragLds(sH1p + ((mt * 8 + kt) * 64 + ld) * 8);
            #pragma unroll
            for (int t = 0; t < 4; ++t) {
                bf16x8 bw = fragGbl(n1p + (size_t)((kt * 16 + wn + 4 * t) * 64 + ld) * 8);
                acc[t] = MFMA(a, bw, acc[t]);
            }
        }
        #pragma unroll
        for (int t = 0; t < 4; ++t) {
            int f = 16 * (wn + 4 * t) + c;
            float bias = fnb1[f];
            int kt2 = f >> 5, lq = (f >> 3) & 3, j2 = f & 7;
            #pragma unroll
            for (int r = 0; r < 4; ++r) {
                float val = lrelu(acc[t][r] + bias);
                sH2p[((mt * 8 + kt2) * 64 + (rlo + r) + 16 * lq) * 8 + j2] = f2bfu(val);
            }
        }
    }
    __syncthreads();

    // ---- node layer 2: K=256 (8 kt), N=32 (2 nt), linear -> out ----
    if (wv < 4) {
        int mt2 = wv >> 1, nt = wv & 1;
        fx4 acc = (fx4){0.f, 0.f, 0.f, 0.f};
        for (int kt = 0; kt < 8; ++kt) {
            bf16x8 a = fragLds(sH2p + ((mt2 * 8 + kt) * 64 + ld) * 8);
            bf16x8 bw = fragGbl(n2p + (size_t)((kt * 2 + nt) * 64 + ld) * 8);
            acc = MFMA(a, bw, acc);
        }
        int f = 16 * nt + c;
        float bias = fnb2[f];
        #pragma unroll
        for (int r = 0; r < 4; ++r) {
            int g = 32 * blk + 16 * mt2 + rlo + r;
            out[(size_t)g * FOUT + f] = acc[r] + bias;
        }
    }
}

extern "C" void kernel_launch(void* const* d_in, const int* in_sizes, int n_in,
                              void* d_out, int out_size, void* d_ws, size_t ws_size,
                              hipStream_t stream) {
    const float* x    = (const float*)d_in[0];
    const float* few0 = (const float*)d_in[1];
    const float* feb0 = (const float*)d_in[2];
    const float* few1 = (const float*)d_in[3];
    const float* feb1 = (const float*)d_in[4];
    const float* few2 = (const float*)d_in[5];
    const float* feb2 = (const float*)d_in[6];
    const float* fnw0 = (const float*)d_in[7];
    const float* fnb0 = (const float*)d_in[8];
    const float* fnw1 = (const float*)d_in[9];
    const float* fnb1 = (const float*)d_in[10];
    const float* fnw2 = (const float*)d_in[11];
    const float* fnb2 = (const float*)d_in[12];

    char* w = (char*)d_ws;
    float* P    = (float*)(w + OFF_P);
    float* V    = (float*)(w + OFF_V);
    u16*   agg  = (u16*)(w + OFF_AGG);
    u16*   pack = (u16*)(w + OFF_PACK);

    prep_kernel<<<PV_BLOCKS + PACK_BLOCKS, 512, 0, stream>>>(
        x, few0, feb0, few1, few2, fnw0, fnw1, fnw2, P, V, pack);

    edge_kernel<<<dim3(N_, B_), 512, 0, stream>>>(
        P, V, pack + PK_W1, pack + PK_W2, feb1, feb2, agg);

    node_kernel<<<200, 512, 0, stream>>>(
        agg, x, pack + PK_N0, pack + PK_N1, pack + PK_N2,
        fnb0, fnb1, fnb2, (float*)d_out);
}